// Round 4
// baseline (162.404 us; speedup 1.0000x reference)
//
#include <hip/hip_runtime.h>

// Complex magnitude max-pool 2x2 (stride 2, VALID), NHWC.
// Input: x_real, x_imag [8,512,512,32] f32. Output: [8,256,256,32,2] f32.
// Identity: mag*cos(atan2(im,re)) == re, mag*sin(...) == im, so the op is an
// argmax(|x|)-gather of (re,im) over each 2x2 window.
// Argmax key computed bit-exactly like numpy (rounded mul/mul/add + IEEE
// sqrt, no fma contraction); strict '>' = first-occurrence tie-break.
//
// R2: latency-bound fix — 8 channels/thread => 16 float4 loads in flight
// (R1 had VGPR=32, compiler serialized loads; MLP too low for ~900cy HBM).
// R3: nontemporal_store needs a native vector type, not HIP float4 class.

typedef float f32x4 __attribute__((ext_vector_type(4)));

constexpr int B  = 8;
constexpr int H  = 512;
constexpr int W  = 512;
constexpr int C  = 32;
constexpr int Ho = H / 2;
constexpr int Wo = W / 2;
constexpr int CG = 8;                      // channels per thread
constexpr long TOTAL = (long)B * Ho * Wo * (C / CG);   // 2,097,152

__device__ __forceinline__ float ref_mag(float r, float i) {
  return __fsqrt_rn(__fadd_rn(__fmul_rn(r, r), __fmul_rn(i, i)));
}

__global__ __launch_bounds__(256, 4) void cmaxpool_kernel(
    const float* __restrict__ xr,
    const float* __restrict__ xi,
    float* __restrict__ out) {
  const long stride = (long)gridDim.x * blockDim.x;
  for (long g = (long)blockIdx.x * blockDim.x + threadIdx.x; g < TOTAL; g += stride) {
    const int c8 = (int)(g & 3);          // C/8 = 4 channel groups
    long t = g >> 2;
    const int wo = (int)(t & (Wo - 1));   t >>= 8;
    const int ho = (int)(t & (Ho - 1));   t >>= 8;
    const int b  = (int)t;
    const int c  = c8 * 8;

    const long ibase = ((((long)b * H + 2 * ho) * W) + 2 * wo) * C + c;
    const long rowstep = (long)W * C;
    // 4 window positions in jnp.argmax order: (0,0),(0,1),(1,0),(1,1)
    const long off[4] = {0, C, rowstep, rowstep + C};

    // Issue all 16 loads before any consumption (MLP).
    f32x4 R[4][2], I[4][2];
#pragma unroll
    for (int k = 0; k < 4; ++k) {
      R[k][0] = *(const f32x4*)(xr + ibase + off[k]);
      R[k][1] = *(const f32x4*)(xr + ibase + off[k] + 4);
    }
#pragma unroll
    for (int k = 0; k < 4; ++k) {
      I[k][0] = *(const f32x4*)(xi + ibase + off[k]);
      I[k][1] = *(const f32x4*)(xi + ibase + off[k] + 4);
    }

    float ore[8], oim[8];
#pragma unroll
    for (int j = 0; j < 8; ++j) {
      const int q = j >> 2, r = j & 3;
      float br = R[0][q][r];
      float bi = I[0][q][r];
      float bm = ref_mag(br, bi);
#pragma unroll
      for (int k = 1; k < 4; ++k) {
        const float rr = R[k][q][r];
        const float ii = I[k][q][r];
        const float m  = ref_mag(rr, ii);
        if (m > bm) { bm = m; br = rr; bi = ii; }   // strict > == first-wins
      }
      ore[j] = br;
      oim[j] = bi;
    }

    // Output layout [B,Ho,Wo,C,2]; 16 consecutive floats, 64B-aligned.
    const long obase = ((((long)b * Ho + ho) * Wo + wo) * C + c) * 2;
#pragma unroll
    for (int s = 0; s < 4; ++s) {
      f32x4 o;
      o.x = ore[2 * s];     o.y = oim[2 * s];
      o.z = ore[2 * s + 1]; o.w = oim[2 * s + 1];
      __builtin_nontemporal_store(o, (f32x4*)(out + obase + 4 * s));
    }
  }
}

extern "C" void kernel_launch(void* const* d_in, const int* in_sizes, int n_in,
                              void* d_out, int out_size, void* d_ws, size_t ws_size,
                              hipStream_t stream) {
  const float* xr = (const float*)d_in[0];
  const float* xi = (const float*)d_in[1];
  float* out = (float*)d_out;

  const int block = 256;
  int grid = (int)((TOTAL + block - 1) / block);
  if (grid > 2048) grid = 2048;   // 4 grid-stride iterations per thread
  cmaxpool_kernel<<<grid, block, 0, stream>>>(xr, xi, out);
}

// Round 5
// 128.485 us; speedup vs baseline: 1.2640x; 1.2640x over previous
//
#include <hip/hip_runtime.h>

// Complex magnitude max-pool 2x2 (stride 2, VALID), NHWC.
// Input: x_real, x_imag [8,512,512,32] f32. Output: [8,256,256,32,2] f32.
// Identity: mag*cos(atan2(im,re)) == re, mag*sin(...) == im, so the op is an
// argmax(|x|)-gather of (re,im) over each 2x2 window.
// Argmax key computed bit-exactly like numpy (rounded mul/mul/add + IEEE
// sqrt, no fma contraction); strict '>' = first-occurrence tie-break.
//
// R4: revert NT stores (write amplification 132->200MB) and 8ch/thread
// (VGPR stayed 32, no MLP gain). Instead: ping-pong register double-buffer
// across grid-stride iterations + sched_barrier(0) so each batch of 8
// global_load_dwordx4 is issued before consuming the previous batch
// (counted-vmcnt overlap).

typedef float f32x4 __attribute__((ext_vector_type(4)));

constexpr int B  = 8;
constexpr int H  = 512;
constexpr int W  = 512;
constexpr int C  = 32;
constexpr int Ho = H / 2;
constexpr int Wo = W / 2;
constexpr long TOTAL = (long)B * Ho * Wo * (C / 4);   // 4,194,304 work items
constexpr int  BLOCK = 256;
constexpr int  GRID  = 2048;
constexpr int  ITERS = (int)(TOTAL / ((long)BLOCK * GRID));   // 8, exact
static_assert((long)BLOCK * GRID * ITERS == TOTAL, "exact tiling");

__device__ __forceinline__ float ref_mag(float r, float i) {
  return __fsqrt_rn(__fadd_rn(__fmul_rn(r, r), __fmul_rn(i, i)));
}

struct Frag { f32x4 R[4], I[4]; };

__device__ __forceinline__ void load_frag(const float* __restrict__ xr,
                                          const float* __restrict__ xi,
                                          long g, Frag& f) {
  const int c4 = (int)(g & 7);          // C/4 = 8 channel groups
  long t = g >> 3;
  const int wo = (int)(t & (Wo - 1));   t >>= 8;
  const int ho = (int)(t & (Ho - 1));   t >>= 8;
  const int b  = (int)t;
  const long ibase = ((((long)b * H + 2 * ho) * W) + 2 * wo) * C + c4 * 4;
  const long rs = (long)W * C;
  // 4 window positions in jnp.argmax order: (0,0),(0,1),(1,0),(1,1)
  f.R[0] = *(const f32x4*)(xr + ibase);
  f.R[1] = *(const f32x4*)(xr + ibase + C);
  f.R[2] = *(const f32x4*)(xr + ibase + rs);
  f.R[3] = *(const f32x4*)(xr + ibase + rs + C);
  f.I[0] = *(const f32x4*)(xi + ibase);
  f.I[1] = *(const f32x4*)(xi + ibase + C);
  f.I[2] = *(const f32x4*)(xi + ibase + rs);
  f.I[3] = *(const f32x4*)(xi + ibase + rs + C);
}

__device__ __forceinline__ void compute_store(float* __restrict__ out,
                                              long g, const Frag& f) {
  const int c4 = (int)(g & 7);
  long t = g >> 3;
  const int wo = (int)(t & (Wo - 1));   t >>= 8;
  const int ho = (int)(t & (Ho - 1));   t >>= 8;
  const int b  = (int)t;

  float ore[4], oim[4];
#pragma unroll
  for (int j = 0; j < 4; ++j) {
    float br = f.R[0][j];
    float bi = f.I[0][j];
    float bm = ref_mag(br, bi);
#pragma unroll
    for (int k = 1; k < 4; ++k) {
      const float rr = f.R[k][j];
      const float ii = f.I[k][j];
      const float m  = ref_mag(rr, ii);
      if (m > bm) { bm = m; br = rr; bi = ii; }   // strict > == first-wins
    }
    ore[j] = br;
    oim[j] = bi;
  }

  // Output layout [B,Ho,Wo,C,2]; base is 32B-aligned (c % 4 == 0).
  const long obase = ((((long)b * Ho + ho) * Wo + wo) * C + c4 * 4) * 2;
  f32x4 o0, o1;
  o0.x = ore[0]; o0.y = oim[0]; o0.z = ore[1]; o0.w = oim[1];
  o1.x = ore[2]; o1.y = oim[2]; o1.z = ore[3]; o1.w = oim[3];
  *(f32x4*)(out + obase)     = o0;
  *(f32x4*)(out + obase + 4) = o1;
}

__global__ __launch_bounds__(BLOCK) void cmaxpool_kernel(
    const float* __restrict__ xr,
    const float* __restrict__ xi,
    float* __restrict__ out) {
  const long stride = (long)GRID * BLOCK;
  long g = (long)blockIdx.x * BLOCK + threadIdx.x;

  Frag fa, fb;
  load_frag(xr, xi, g, fa);
#pragma unroll
  for (int it = 0; it < ITERS; it += 2) {
    // prefetch B while A is in flight / being consumed
    if (it + 1 < ITERS) load_frag(xr, xi, g + stride, fb);
    __builtin_amdgcn_sched_barrier(0);   // keep prefetch issued before consume
    compute_store(out, g, fa);
    if (it + 2 < ITERS) load_frag(xr, xi, g + 2 * stride, fa);
    __builtin_amdgcn_sched_barrier(0);
    if (it + 1 < ITERS) compute_store(out, g + stride, fb);
    g += 2 * stride;
  }
}

extern "C" void kernel_launch(void* const* d_in, const int* in_sizes, int n_in,
                              void* d_out, int out_size, void* d_ws, size_t ws_size,
                              hipStream_t stream) {
  const float* xr = (const float*)d_in[0];
  const float* xi = (const float*)d_in[1];
  float* out = (float*)d_out;
  cmaxpool_kernel<<<GRID, BLOCK, 0, stream>>>(xr, xi, out);
}